// Round 11
// baseline (125.141 us; speedup 1.0000x reference)
//
#include <hip/hip_runtime.h>
#include <math.h>

// Problem constants
#define D_DOM 64
#define S_RES 512
#define R_ROWS 2048
#define NAA 20
#define NF 12
#define NB 2
#define NJ 24       // NB*NF
#define NPC 8       // p-chunks per domain (256 rows each)
#define SUB 8       // rows per stage sub-batch (16 KB f32)
#define NSUB 32     // sub-batches per block
#define NSB 8       // super-batches per block (32 rows = 16 p each)
#define BSTR 520    // bf16 row stride (+8 pad)

typedef unsigned short ushort_t;
typedef unsigned int uint_t;
typedef short bf16x8 __attribute__((ext_vector_type(8)));   // 8 bf16 = 4 VGPR
typedef float f32x4 __attribute__((ext_vector_type(4)));

// bf16 helpers (RNE), dependency-free — validated R4-R10
__device__ __forceinline__ ushort_t f2bf(float x) {
  uint_t u = __float_as_uint(x);
  uint_t r = u + 0x7FFFu + ((u >> 16) & 1u);
  return (ushort_t)(r >> 16);
}
__device__ __forceinline__ float bflo(uint_t u) { return __uint_as_float(u << 16); }
__device__ __forceinline__ float bfhi(uint_t u) { return __uint_as_float(u & 0xFFFF0000u); }
__device__ __forceinline__ float bf2f(ushort_t h) {
  return __uint_as_float(((uint_t)h) << 16);
}
__device__ __forceinline__ uint_t pk2(float a, float b) {
  return (uint_t)f2bf(a) | ((uint_t)f2bf(b) << 16);
}

// Direct global->LDS DMA, 16 B/lane (dest wave-uniform base).
__device__ __forceinline__ void gload_lds16(const float* g, float* l) {
  __builtin_amdgcn_global_load_lds((const __attribute__((address_space(1))) void*)g,
                                   (__attribute__((address_space(3))) void*)l,
                                   16, 0, 0);
}

// ---------------------------------------------------------------------------
// Kernel A (R10): G[d][j][k] bf16 (k<512: g0[j,s]; k>=512: g1[j,s]).
// ---------------------------------------------------------------------------
__global__ __launch_bounds__(256) void kA_g(const float* __restrict__ aa,
                                            const float* __restrict__ wconv,
                                            ushort_t* __restrict__ g) {
  __shared__ float ws[NF * NAA * 2];
  const int tid = threadIdx.x;
  for (int i = tid; i < NF * NAA * 2; i += 256) ws[i] = wconv[i];
  __syncthreads();
  const int pos = blockIdx.x * 256 + tid;  // d*512 + s
  const int b = blockIdx.y;
  float av[NAA];
#pragma unroll
  for (int c = 0; c < NAA; ++c)
    av[c] = aa[(size_t)(b * NAA + c) * (D_DOM * S_RES) + pos];
  const int d = pos >> 9;
  const int s = pos & 511;
#pragma unroll
  for (int f = 0; f < NF; ++f) {
    float s0 = 0.f, s1 = 0.f;
#pragma unroll
    for (int c = 0; c < NAA; ++c) {
      const float a = av[c];
      s0 = fmaf(a, ws[(f * NAA + c) * 2 + 0], s0);
      s1 = fmaf(a, ws[(f * NAA + c) * 2 + 1], s1);
    }
    const int j = b * NF + f;
    g[((size_t)(d * NJ + j)) * 1024 + s] = f2bf(s0);
    g[((size_t)(d * NJ + j)) * 1024 + 512 + s] = f2bf(s1);
  }
}

// ---------------------------------------------------------------------------
// Kernel B v11: 16-p super-batches, single Bs16 buffer.
// 512 blocks x 256 thr (4 waves); block=(d,pc) covers 256 rows (128 p) as
// 8 super-batches x 32 rows (16 p), staged in 8-row sub-batches.
// Per super-batch T:
//   4x { [counted vmcnt] cvt(sub)+deg-f32 ; STAGE(sub+2) }   (rows dbuf)
//   lgkm+barrier; MFMA: 16x mfma_16x16x32_bf16, B cols = 16 DISTINCT p
//     (p=jl, R7-validated addressing; 4x fewer B-frag reads than R9/R10)
//   lgkm+barrier; y-phase: yv += h[j,p]*Ae[p,s] (hs reads broadcast)
//   lgkm+barrier (Bs16 free for T+1)
// vmcnt never drains mid-loop except last sub. STAGE(sb+2) write of
// rows[sb&1] is safe: same wave's cvt reads retired before issue (in-order
// wave + lgkm dependency through pk2). NO min-waves bound (R5), no
// reg-staging (R7). LDS 70,144 B -> 2 blocks/CU.
// ---------------------------------------------------------------------------
__global__ __launch_bounds__(256) void kB_main(const float* __restrict__ adjs,
                                               const ushort_t* __restrict__ g,
                                               ushort_t* __restrict__ yp,
                                               float* __restrict__ degp) {
  const int tid = threadIdx.x;
  const int w = tid >> 6;   // 0..3
  const int l = tid & 63;
  const int d = blockIdx.x >> 3;
  const int pc = blockIdx.x & 7;

  const int mt = w & 1, kh = w >> 1;
  const int jl = l & 15, kg = l >> 4;

  __shared__ float rows[2][SUB][S_RES];                    // 32 KB f32 (dbuf)
  __shared__ __align__(16) ushort_t Bs16[4 * SUB][BSTR];   // 33.25 KB (single)
  __shared__ __align__(16) float hs[2][32][16];            // [kh][j][p] 4 KB

  const float* ablk = adjs + ((size_t)d * R_ROWS + (size_t)pc * 256) * S_RES;

  // A-frags: wave's (mt, kh): 16 ksteps x 8 bf16 (loop-invariant, 64 VGPR)
  bf16x8 gf[16];
  {
    const int j_a = mt * 16 + jl;
    const bool valid = (j_a < NJ);
    const ushort_t* gr =
        g + ((size_t)(d * NJ + (valid ? j_a : 0))) * 1024 + kh * 512 + kg * 8;
    const bf16x8 z = {};
#pragma unroll
    for (int ks = 0; ks < 16; ++ks) {
      bf16x8 v = *(const bf16x8*)(gr + ks * 32);
      gf[ks] = valid ? v : z;
    }
  }

#define STAGE(SB)                                                              \
  {                                                                            \
    _Pragma("unroll")                                                          \
    for (int q = 0; q < 4; ++q) {                                              \
      const int u_ = w * 4 + q;                                                \
      const int row_ = u_ >> 1;                                                \
      const int half_ = u_ & 1;                                                \
      gload_lds16(ablk + ((size_t)((SB)*SUB + row_)) * S_RES + half_ * 256 +   \
                      l * 4,                                                   \
                  &rows[(SB) & 1][row_][half_ * 256]);                         \
    }                                                                          \
  }

  STAGE(0);
  STAGE(1);
  asm volatile("s_waitcnt vmcnt(0)" ::: "memory");  // gf + subs 0,1 resident

  float yv[6][8];
#pragma unroll
  for (int jj = 0; jj < 6; ++jj)
#pragma unroll
    for (int e = 0; e < 8; ++e) yv[jj][e] = 0.f;
  float dg[16];  // f32 deg partial: rows == (tid>>5) mod 8, s = (tid&31)*16..+15
#pragma unroll
  for (int e = 0; e < 16; ++e) dg[e] = 0.f;

  const int r_ = tid >> 5;          // cvt row within sub-batch (0..7)
  const int c0 = (tid & 31) * 16;   // cvt col chunk

  for (int T = 0; T < NSB; ++T) {
#pragma unroll
    for (int u = 0; u < 4; ++u) {
      const int sb = T * 4 + u;
      if (sb >= 2) {
        if (sb < NSUB - 1) {
          asm volatile("s_waitcnt vmcnt(4)" ::: "memory");  // sub sb resident
        } else {
          asm volatile("s_waitcnt vmcnt(0)" ::: "memory");
        }
      }
      // cvt: rows[sb&1] f32 -> Bs16 rows u*8.., + f32 deg accumulate
      {
        const float4 a = *(const float4*)&rows[sb & 1][r_][c0];
        const float4 b = *(const float4*)&rows[sb & 1][r_][c0 + 4];
        const float4 c = *(const float4*)&rows[sb & 1][r_][c0 + 8];
        const float4 e = *(const float4*)&rows[sb & 1][r_][c0 + 12];
        dg[0] += a.x;  dg[1] += a.y;  dg[2] += a.z;  dg[3] += a.w;
        dg[4] += b.x;  dg[5] += b.y;  dg[6] += b.z;  dg[7] += b.w;
        dg[8] += c.x;  dg[9] += c.y;  dg[10] += c.z; dg[11] += c.w;
        dg[12] += e.x; dg[13] += e.y; dg[14] += e.z; dg[15] += e.w;
        uint4 o0, o1;
        o0.x = pk2(a.x, a.y); o0.y = pk2(a.z, a.w);
        o0.z = pk2(b.x, b.y); o0.w = pk2(b.z, b.w);
        o1.x = pk2(c.x, c.y); o1.y = pk2(c.z, c.w);
        o1.z = pk2(e.x, e.y); o1.w = pk2(e.z, e.w);
        *(uint4*)&Bs16[u * SUB + r_][c0] = o0;
        *(uint4*)&Bs16[u * SUB + r_][c0 + 8] = o1;
      }
      if (sb + 2 < NSUB) STAGE(sb + 2);
    }

    asm volatile("s_waitcnt lgkmcnt(0)\n\ts_barrier" ::: "memory");  // Bs16 ready

    // h-MFMA(T): 16 x 16x16x32; B col = p = jl (16 distinct p, R7 layout)
    {
      f32x4 acc = {0.f, 0.f, 0.f, 0.f};
#pragma unroll
      for (int ks = 0; ks < 16; ++ks) {
        const bf16x8 bfr = *(const bf16x8*)&Bs16[2 * jl + kh][ks * 32 + kg * 8];
        acc = __builtin_amdgcn_mfma_f32_16x16x32_bf16(gf[ks], bfr, acc, 0, 0, 0);
      }
#pragma unroll
      for (int i = 0; i < 4; ++i) hs[kh][mt * 16 + kg * 4 + i][jl] = acc[i];
    }

    asm volatile("s_waitcnt lgkmcnt(0)\n\ts_barrier" ::: "memory");  // hs ready

    // y-phase(T): yv[jj][e] += sum_p (hs[0]+hs[1])[j][p] * Ae[p][s]
#pragma unroll
    for (int pg = 0; pg < 4; ++pg) {
      float ae[4][8];
#pragma unroll
      for (int q = 0; q < 4; ++q) {
        const uint4 v = *(const uint4*)&Bs16[2 * (pg * 4 + q)][l * 8];
        ae[q][0] = bflo(v.x); ae[q][1] = bfhi(v.x);
        ae[q][2] = bflo(v.y); ae[q][3] = bfhi(v.y);
        ae[q][4] = bflo(v.z); ae[q][5] = bfhi(v.z);
        ae[q][6] = bflo(v.w); ae[q][7] = bfhi(v.w);
      }
#pragma unroll
      for (int jj = 0; jj < 6; ++jj) {
        const int j_ = w * 6 + jj;
        const f32x4 ha = *(const f32x4*)&hs[0][j_][pg * 4];
        const f32x4 hb = *(const f32x4*)&hs[1][j_][pg * 4];
        const f32x4 h4 = ha + hb;
#pragma unroll
        for (int q = 0; q < 4; ++q) {
          const float hv = h4[q];
#pragma unroll
          for (int e = 0; e < 8; ++e) yv[jj][e] = fmaf(hv, ae[q][e], yv[jj][e]);
        }
      }
    }

    asm volatile("s_waitcnt lgkmcnt(0)\n\ts_barrier" ::: "memory");  // Bs16 free
  }

  // y partials -> bf16 yp
  ushort_t* ypb = yp + (size_t)(pc * D_DOM + d) * NJ * S_RES;
#pragma unroll
  for (int jj = 0; jj < 6; ++jj) {
    const int j = w * 6 + jj;
    uint4 o;
    o.x = pk2(yv[jj][0], yv[jj][1]);
    o.y = pk2(yv[jj][2], yv[jj][3]);
    o.z = pk2(yv[jj][4], yv[jj][5]);
    o.w = pk2(yv[jj][6], yv[jj][7]);
    *(uint4*)(ypb + (size_t)j * S_RES + l * 8) = o;
  }
  // deg partials (f32): 8 partial arrays per (d,pc), indexed by tid>>5
  {
    float* dp = degp + (((size_t)(d * NPC + pc)) * 8 + r_) * S_RES + c0;
    *(float4*)dp = make_float4(dg[0], dg[1], dg[2], dg[3]);
    *(float4*)(dp + 4) = make_float4(dg[4], dg[5], dg[6], dg[7]);
    *(float4*)(dp + 8) = make_float4(dg[8], dg[9], dg[10], dg[11]);
    *(float4*)(dp + 12) = make_float4(dg[12], dg[13], dg[14], dg[15]);
  }
}

// ---------------------------------------------------------------------------
// Kernel Df (fused D0+D1+D2): per-domain block: rdeg from 64 partials,
// per-j pc-sum + max-pool, combine, sigmoid. Saves 2 launches (R10 lesson:
// tail launches ~8 us of the budget).
// ---------------------------------------------------------------------------
__global__ __launch_bounds__(256) void kDf(const ushort_t* __restrict__ yp,
                                           const float* __restrict__ degp,
                                           const float* __restrict__ wcomb,
                                           float* __restrict__ out) {
  const int d = blockIdx.x;
  const int tid = threadIdx.x;
  const int tj = tid >> 6;
  __shared__ float wm[NJ][4];
  __shared__ float pool[NJ];

  float dg0 = 0.f, dg1 = 0.f;
  const float* base = degp + (size_t)d * NPC * 8 * S_RES;
#pragma unroll 8
  for (int k = 0; k < NPC * 8; ++k) {
    const float2 dv = *(const float2*)(base + (size_t)k * S_RES + 2 * tid);
    dg0 += dv.x;
    dg1 += dv.y;
  }
  const float q0 = 1.0f / dg0;
  const float q1 = 1.0f / dg1;

  for (int j = 0; j < NJ; ++j) {
    float v0 = 0.f, v1 = 0.f;
#pragma unroll
    for (int pc = 0; pc < NPC; ++pc) {
      const ushort2 yv =
          *(const ushort2*)(yp + ((size_t)(pc * D_DOM + d) * NJ + j) * S_RES + 2 * tid);
      v0 += bf2f(yv.x);
      v1 += bf2f(yv.y);
    }
    float m = fmaxf(v0 * q0, v1 * q1);
#pragma unroll
    for (int mask = 32; mask; mask >>= 1) m = fmaxf(m, __shfl_xor(m, mask));
    if ((tid & 63) == 0) wm[j][tj] = m;
  }
  __syncthreads();
  if (tid < NJ)
    pool[tid] = fmaxf(fmaxf(wm[tid][0], wm[tid][1]), fmaxf(wm[tid][2], wm[tid][3]));
  __syncthreads();
  if (tid < NB) {
    float sc = 0.f;
#pragma unroll
    for (int f = 0; f < NF; ++f) sc = fmaf(pool[tid * NF + f], wcomb[f], sc);
    out[d * NB + tid] = 1.0f / (1.0f + expf(-sc));
  }
}

// ---------------------------------------------------------------------------
extern "C" void kernel_launch(void* const* d_in, const int* in_sizes, int n_in,
                              void* d_out, int out_size, void* d_ws, size_t ws_size,
                              hipStream_t stream) {
  const float* aa = (const float*)d_in[0];
  const float* adjs = (const float*)d_in[1];
  const float* wconv = (const float*)d_in[2];
  const float* wcomb = (const float*)d_in[3];
  float* out = (float*)d_out;
  char* wsb = (char*)d_ws;

  // ws layout (bytes):
  //   g    bf16 [64][24][1024] @ 0          = 3,145,728
  //   yp   bf16 [8*64*24*512]  @ 3,145,728  = 12,582,912
  //   degp f32  [64*8*8*512]   @ 15,728,640 = 8,388,608  (total 24,117,248)
  ushort_t* g = (ushort_t*)wsb;
  ushort_t* yp = (ushort_t*)(wsb + 3145728);
  float* degp = (float*)(wsb + 15728640);

  kA_g<<<dim3(128, 2), dim3(256), 0, stream>>>(aa, wconv, g);
  kB_main<<<dim3(512), dim3(256), 0, stream>>>(adjs, g, yp, degp);
  kDf<<<dim3(64), dim3(256), 0, stream>>>(yp, degp, wcomb, out);
}

// Round 12
// 104.285 us; speedup vs baseline: 1.2000x; 1.2000x over previous
//
#include <hip/hip_runtime.h>
#include <math.h>

// Problem constants
#define D_DOM 64
#define S_RES 512
#define R_ROWS 2048
#define NAA 20
#define NF 12
#define NB 2
#define NJ 24       // NB*NF
#define NPC 8       // p-chunks per domain (256 rows each)
#define BROWS 8     // rows per stage batch (16 KB f32, 4 p)
#define NBATCH 32   // batches per block (256 rows)
#define BSTR 520    // bf16 row stride (+8 pad)

typedef unsigned short ushort_t;
typedef unsigned int uint_t;
typedef short bf16x8 __attribute__((ext_vector_type(8)));   // 8 bf16 = 4 VGPR
typedef float f32x4 __attribute__((ext_vector_type(4)));

// bf16 helpers (RNE), dependency-free — validated R4-R11
__device__ __forceinline__ ushort_t f2bf(float x) {
  uint_t u = __float_as_uint(x);
  uint_t r = u + 0x7FFFu + ((u >> 16) & 1u);
  return (ushort_t)(r >> 16);
}
__device__ __forceinline__ float bflo(uint_t u) { return __uint_as_float(u << 16); }
__device__ __forceinline__ float bfhi(uint_t u) { return __uint_as_float(u & 0xFFFF0000u); }
__device__ __forceinline__ float bf2f(ushort_t h) {
  return __uint_as_float(((uint_t)h) << 16);
}
__device__ __forceinline__ uint_t pk2(float a, float b) {
  return (uint_t)f2bf(a) | ((uint_t)f2bf(b) << 16);
}

// Direct global->LDS DMA, 16 B/lane (dest wave-uniform base).
__device__ __forceinline__ void gload_lds16(const float* g, float* l) {
  __builtin_amdgcn_global_load_lds((const __attribute__((address_space(1))) void*)g,
                                   (__attribute__((address_space(3))) void*)l,
                                   16, 0, 0);
}

// ---------------------------------------------------------------------------
// Kernel A (R10, unchanged): G[d][j][k] bf16.
// ---------------------------------------------------------------------------
__global__ __launch_bounds__(256) void kA_g(const float* __restrict__ aa,
                                            const float* __restrict__ wconv,
                                            ushort_t* __restrict__ g) {
  __shared__ float ws[NF * NAA * 2];
  const int tid = threadIdx.x;
  for (int i = tid; i < NF * NAA * 2; i += 256) ws[i] = wconv[i];
  __syncthreads();
  const int pos = blockIdx.x * 256 + tid;  // d*512 + s
  const int b = blockIdx.y;
  float av[NAA];
#pragma unroll
  for (int c = 0; c < NAA; ++c)
    av[c] = aa[(size_t)(b * NAA + c) * (D_DOM * S_RES) + pos];
  const int d = pos >> 9;
  const int s = pos & 511;
#pragma unroll
  for (int f = 0; f < NF; ++f) {
    float s0 = 0.f, s1 = 0.f;
#pragma unroll
    for (int c = 0; c < NAA; ++c) {
      const float a = av[c];
      s0 = fmaf(a, ws[(f * NAA + c) * 2 + 0], s0);
      s1 = fmaf(a, ws[(f * NAA + c) * 2 + 1], s1);
    }
    const int j = b * NF + f;
    g[((size_t)(d * NJ + j)) * 1024 + s] = f2bf(s0);
    g[((size_t)(d * NJ + j)) * 1024 + 512 + s] = f2bf(s1);
  }
}

// ---------------------------------------------------------------------------
// Kernel B — R10 VERBATIM (94.7 us config). v11's single-buffer super-batch
// regressed 30 us: staging only issued during cvt phase -> HBM idle under
// MFMA/y + 3 barriers. This 2-barrier lagged-y pipeline keeps prefetch
// continuously in flight. Do not trade overlap for LDS-read count (R11).
// ---------------------------------------------------------------------------
__global__ __launch_bounds__(256) void kB_main(const float* __restrict__ adjs,
                                               const ushort_t* __restrict__ g,
                                               ushort_t* __restrict__ yp,
                                               float* __restrict__ degp) {
  const int tid = threadIdx.x;
  const int w = tid >> 6;   // 0..3
  const int l = tid & 63;
  const int d = blockIdx.x >> 3;
  const int pc = blockIdx.x & 7;

  const int mt = w & 1, kh = w >> 1;
  const int jl = l & 15, kg = l >> 4;
  const int pl = jl & 3;  // B-frag p (cols 4-15 duplicate 0-3, ignored)

  __shared__ float rows[2][BROWS][S_RES];                  // 32 KB f32 (dbuf)
  __shared__ __align__(16) ushort_t Bs16[2][BROWS][BSTR];  // 16.25 KB (dbuf)
  __shared__ __align__(16) float hs[2][2][2][16][4];       // 4 KB

  const float* ablk = adjs + ((size_t)d * R_ROWS + (size_t)pc * 256) * S_RES;

  // A-frags: wave's (mt, kh): 16 ksteps x 8 bf16 (loop-invariant, 64 VGPR)
  bf16x8 gf[16];
  {
    const int j_a = mt * 16 + jl;
    const bool valid = (j_a < NJ);
    const ushort_t* gr =
        g + ((size_t)(d * NJ + (valid ? j_a : 0))) * 1024 + kh * 512 + kg * 8;
    const bf16x8 z = {};
#pragma unroll
    for (int ks = 0; ks < 16; ++ks) {
      bf16x8 v = *(const bf16x8*)(gr + ks * 32);
      gf[ks] = valid ? v : z;
    }
  }

  float yv[6][8];
#pragma unroll
  for (int jj = 0; jj < 6; ++jj)
#pragma unroll
    for (int e = 0; e < 8; ++e) yv[jj][e] = 0.f;
  float dgv[8];
#pragma unroll
  for (int e = 0; e < 8; ++e) dgv[e] = 0.f;

#define STAGE(T)                                                               \
  {                                                                            \
    _Pragma("unroll")                                                          \
    for (int q = 0; q < 4; ++q) {                                              \
      const int u_ = w * 4 + q;                                                \
      const int row_ = u_ >> 1;                                                \
      const int half_ = u_ & 1;                                                \
      gload_lds16(ablk + ((size_t)((T)*BROWS + row_)) * S_RES + half_ * 256 +  \
                      l * 4,                                                   \
                  &rows[(T) & 1][row_][half_ * 256]);                          \
    }                                                                          \
  }

#define Y_PHASE(TT)                                                            \
  {                                                                            \
    const int buf_ = (TT) & 1;                                                 \
    float ae[4][8];                                                            \
    _Pragma("unroll") for (int p = 0; p < 4; ++p) {                            \
      const uint4 v = *(const uint4*)&Bs16[buf_][p * 2][l * 8];                \
      ae[p][0] = bflo(v.x); ae[p][1] = bfhi(v.x);                              \
      ae[p][2] = bflo(v.y); ae[p][3] = bfhi(v.y);                              \
      ae[p][4] = bflo(v.z); ae[p][5] = bfhi(v.z);                              \
      ae[p][6] = bflo(v.w); ae[p][7] = bfhi(v.w);                              \
    }                                                                          \
    _Pragma("unroll") for (int jj = 0; jj < 6; ++jj) {                         \
      const int j_ = w * 6 + jj;                                               \
      const int jt_ = j_ >> 4, jlo_ = j_ & 15;                                 \
      const f32x4 ha = *(const f32x4*)&hs[buf_][0][jt_][jlo_][0];              \
      const f32x4 hb = *(const f32x4*)&hs[buf_][1][jt_][jlo_][0];              \
      const f32x4 h4 = ha + hb;                                                \
      _Pragma("unroll") for (int p = 0; p < 4; ++p) {                          \
        const float hv = h4[p];                                                \
        _Pragma("unroll") for (int e = 0; e < 8; ++e)                          \
            yv[jj][e] = fmaf(hv, ae[p][e], yv[jj][e]);                         \
      }                                                                        \
    }                                                                          \
  }

  STAGE(0);

  for (int t = 0; t < NBATCH; ++t) {
    asm volatile("s_waitcnt vmcnt(0)" ::: "memory");  // STAGE(t) resident
    asm volatile("s_waitcnt lgkmcnt(0)\n\ts_barrier" ::: "memory");  // A
    if (t + 1 < NBATCH) STAGE(t + 1);

    // cvt(t): rows[t&1] f32 -> Bs16[t&1] bf16. 16 elems/thread.
    {
      const int r_ = tid >> 5;
      const int c0 = (tid & 31) * 16;
      const float4 a = *(const float4*)&rows[t & 1][r_][c0];
      const float4 b = *(const float4*)&rows[t & 1][r_][c0 + 4];
      const float4 c = *(const float4*)&rows[t & 1][r_][c0 + 8];
      const float4 e = *(const float4*)&rows[t & 1][r_][c0 + 12];
      uint4 o0, o1;
      o0.x = pk2(a.x, a.y); o0.y = pk2(a.z, a.w);
      o0.z = pk2(b.x, b.y); o0.w = pk2(b.z, b.w);
      o1.x = pk2(c.x, c.y); o1.y = pk2(c.z, c.w);
      o1.z = pk2(e.x, e.y); o1.w = pk2(e.z, e.w);
      *(uint4*)&Bs16[t & 1][r_][c0] = o0;
      *(uint4*)&Bs16[t & 1][r_][c0 + 8] = o1;
    }

    if (t) Y_PHASE(t - 1);  // lagged y: (t-1)&1 buffers stable

    asm volatile("s_waitcnt lgkmcnt(0)\n\ts_barrier" ::: "memory");  // B

    // deg(t): wave w sums bf16 rows 2w, 2w+1 (lane's 8 s)
#pragma unroll
    for (int rr = 0; rr < 2; ++rr) {
      const uint4 v = *(const uint4*)&Bs16[t & 1][2 * w + rr][l * 8];
      dgv[0] += bflo(v.x); dgv[1] += bfhi(v.x);
      dgv[2] += bflo(v.y); dgv[3] += bfhi(v.y);
      dgv[4] += bflo(v.z); dgv[5] += bfhi(v.z);
      dgv[6] += bflo(v.w); dgv[7] += bfhi(v.w);
    }

    // h-MFMA(t): 16 x 16x16x32 (R7/R9-validated layout)
    {
      f32x4 acc = {0.f, 0.f, 0.f, 0.f};
#pragma unroll
      for (int ks = 0; ks < 16; ++ks) {
        const bf16x8 bfr =
            *(const bf16x8*)&Bs16[t & 1][pl * 2 + kh][ks * 32 + kg * 8];
        acc = __builtin_amdgcn_mfma_f32_16x16x32_bf16(gf[ks], bfr, acc, 0, 0, 0);
      }
      if (jl < 4) {
#pragma unroll
        for (int i = 0; i < 4; ++i) hs[t & 1][kh][mt][kg * 4 + i][jl] = acc[i];
      }
    }
  }

  asm volatile("s_waitcnt lgkmcnt(0)\n\ts_barrier" ::: "memory");
  Y_PHASE(NBATCH - 1);

  // y partials -> bf16 yp; deg partials -> degp f32
  ushort_t* ypb = yp + (size_t)(pc * D_DOM + d) * NJ * S_RES;
#pragma unroll
  for (int jj = 0; jj < 6; ++jj) {
    const int j = w * 6 + jj;
    uint4 o;
    o.x = pk2(yv[jj][0], yv[jj][1]);
    o.y = pk2(yv[jj][2], yv[jj][3]);
    o.z = pk2(yv[jj][4], yv[jj][5]);
    o.w = pk2(yv[jj][6], yv[jj][7]);
    *(uint4*)(ypb + (size_t)j * S_RES + l * 8) = o;
  }
  {
    float* dp = degp + (((size_t)(d * NPC + pc)) * 4 + w) * S_RES + l * 8;
    *(float4*)dp = make_float4(dgv[0], dgv[1], dgv[2], dgv[3]);
    *(float4*)(dp + 4) = make_float4(dgv[4], dgv[5], dgv[6], dgv[7]);
  }
}

// ---------------------------------------------------------------------------
// Kernel Df (fused D0+D1+D2, adapted to R10 degp layout [d][pc][w][512]):
// per-domain block: rdeg from 32 partials, per-j pc-sum + max-pool,
// combine, sigmoid. Saves 2 launches vs R10.
// ---------------------------------------------------------------------------
__global__ __launch_bounds__(256) void kDf(const ushort_t* __restrict__ yp,
                                           const float* __restrict__ degp,
                                           const float* __restrict__ wcomb,
                                           float* __restrict__ out) {
  const int d = blockIdx.x;
  const int tid = threadIdx.x;
  const int tj = tid >> 6;
  __shared__ float wm[NJ][4];
  __shared__ float pool[NJ];

  float dg0 = 0.f, dg1 = 0.f;
  const float* base = degp + (size_t)d * NPC * 4 * S_RES;
#pragma unroll 8
  for (int k = 0; k < NPC * 4; ++k) {
    const float2 dv = *(const float2*)(base + (size_t)k * S_RES + 2 * tid);
    dg0 += dv.x;
    dg1 += dv.y;
  }
  const float q0 = 1.0f / dg0;
  const float q1 = 1.0f / dg1;

  for (int j = 0; j < NJ; ++j) {
    float v0 = 0.f, v1 = 0.f;
#pragma unroll
    for (int pc = 0; pc < NPC; ++pc) {
      const ushort2 yv =
          *(const ushort2*)(yp + ((size_t)(pc * D_DOM + d) * NJ + j) * S_RES + 2 * tid);
      v0 += bf2f(yv.x);
      v1 += bf2f(yv.y);
    }
    float m = fmaxf(v0 * q0, v1 * q1);
#pragma unroll
    for (int mask = 32; mask; mask >>= 1) m = fmaxf(m, __shfl_xor(m, mask));
    if ((tid & 63) == 0) wm[j][tj] = m;
  }
  __syncthreads();
  if (tid < NJ)
    pool[tid] = fmaxf(fmaxf(wm[tid][0], wm[tid][1]), fmaxf(wm[tid][2], wm[tid][3]));
  __syncthreads();
  if (tid < NB) {
    float sc = 0.f;
#pragma unroll
    for (int f = 0; f < NF; ++f) sc = fmaf(pool[tid * NF + f], wcomb[f], sc);
    out[d * NB + tid] = 1.0f / (1.0f + expf(-sc));
  }
}

// ---------------------------------------------------------------------------
extern "C" void kernel_launch(void* const* d_in, const int* in_sizes, int n_in,
                              void* d_out, int out_size, void* d_ws, size_t ws_size,
                              hipStream_t stream) {
  const float* aa = (const float*)d_in[0];
  const float* adjs = (const float*)d_in[1];
  const float* wconv = (const float*)d_in[2];
  const float* wcomb = (const float*)d_in[3];
  float* out = (float*)d_out;
  char* wsb = (char*)d_ws;

  // ws layout (bytes):
  //   g    bf16 [64][24][1024] @ 0          = 3,145,728
  //   yp   bf16 [8*64*24*512]  @ 3,145,728  = 12,582,912
  //   degp f32  [64*8*4*512]   @ 15,728,640 = 4,194,304  (total ~19.9 MB)
  ushort_t* g = (ushort_t*)wsb;
  ushort_t* yp = (ushort_t*)(wsb + 3145728);
  float* degp = (float*)(wsb + 15728640);

  kA_g<<<dim3(128, 2), dim3(256), 0, stream>>>(aa, wconv, g);
  kB_main<<<dim3(512), dim3(256), 0, stream>>>(adjs, g, yp, degp);
  kDf<<<dim3(64), dim3(256), 0, stream>>>(yp, degp, wcomb, out);
}